// Round 4
// baseline (688.118 us; speedup 1.0000x reference)
//
#include <hip/hip_runtime.h>

typedef __bf16 bf16_t;
typedef bf16_t bf16x8 __attribute__((ext_vector_type(8)));
typedef bf16_t bf16x4 __attribute__((ext_vector_type(4)));
typedef float f32x4 __attribute__((ext_vector_type(4)));
typedef unsigned int u32;

typedef __attribute__((address_space(1))) unsigned as1_u32;
typedef __attribute__((address_space(3))) unsigned as3_u32;

#define LOG2E 1.4426950408889634f
#define QSCALE (0.125f * LOG2E)       // fold softmax scale + log2(e) into Qp
#define MASK2 (-10000.0f * LOG2E)     // additive mask in exp2 domain

// async global->LDS, 16B per lane, LDS dest = wave-uniform base + lane*16
__device__ __forceinline__ void gload16(const void* g, void* l) {
  __builtin_amdgcn_global_load_lds((as1_u32*)(void*)g, (as3_u32*)l, 16, 0, 0);
}

// ---------------------------------------------------------------------------
// fp32 -> bf16 bulk convert, q and kv in one launch. grid 8192, block 256,
// 8 elems/thread. Total 2 x 8M elems.
__global__ void cvt_qkv(const float* __restrict__ q, const float* __restrict__ kv,
                        bf16_t* __restrict__ qb, bf16_t* __restrict__ kvb) {
  long i = ((long)blockIdx.x * 256 + threadIdx.x) * 8;
  const float* src; bf16_t* dst;
  if (i < 8388608) { src = q + i; dst = qb + i; }
  else { src = kv + (i - 8388608); dst = kvb + (i - 8388608); }
  const float4 a = *(const float4*)src;
  const float4 b = *(const float4*)(src + 4);
  bf16x8 o;
  o[0] = (bf16_t)a.x; o[1] = (bf16_t)a.y; o[2] = (bf16_t)a.z; o[3] = (bf16_t)a.w;
  o[4] = (bf16_t)b.x; o[5] = (bf16_t)b.y; o[6] = (bf16_t)b.z; o[7] = (bf16_t)b.w;
  *(bf16x8*)dst = o;
}

// ---------------------------------------------------------------------------
// Mask prep: detect bool-bytes vs int32, build additive float mask (0 / MASK2)
// with the reference's "all-pad row -> unmask last key" fix. grid 8, block 256.
__global__ void prep_mask(const unsigned char* __restrict__ mraw,
                          float* __restrict__ maskf) {
  __shared__ int sred[256];
  const int t = threadIdx.x, b = blockIdx.x;
  // int32 0/1 values have zero bytes at offsets %4!=0; bool-bytes don't.
  int f = 0;
  for (int i = t; i < 2048; i += 256) {
    u32 v = ((const u32*)mraw)[i];
    if (v & 0xFFFFFF00u) f = 1;
  }
  sred[t] = f; __syncthreads();
  for (int s = 128; s; s >>= 1) { if (t < s) sred[t] |= sred[t + s]; __syncthreads(); }
  const int isByte = sred[0];
  __syncthreads();

  int vals[4]; int allpad = 1;
#pragma unroll
  for (int i = 0; i < 4; i++) {
    int k = t * 4 + i;
    int mv = isByte ? (int)mraw[b * 1024 + k] : ((const int*)mraw)[b * 1024 + k];
    vals[i] = (mv != 0);
    allpad &= vals[i];
  }
  sred[t] = allpad; __syncthreads();
  for (int s = 128; s; s >>= 1) { if (t < s) sred[t] &= sred[t + s]; __syncthreads(); }
  const int ap = sred[0];
#pragma unroll
  for (int i = 0; i < 4; i++) {
    int k = t * 4 + i;
    int m = vals[i];
    if (ap && k == 1023) m = 0;
    maskf[b * 1024 + k] = m ? MASK2 : 0.0f;
  }
}

// ---------------------------------------------------------------------------
// All 6 weight transposes (fp32 W[K][N] -> bf16 WT[N][K]) in one launch.
// Exact grid: 4x256 + 1024 + 1024 = 3072 blocks of 256.
struct TP { const float* s; bf16_t* d; int K; int N; };
struct TP6 { TP t[6]; };
__global__ void transpose_all(TP6 args) {
  __shared__ float tile[64][65];
  int bid = blockIdx.x, z, tx, ty;
  if (bid < 1024)      { z = bid >> 8;  int r = bid & 255;  tx = r & 15; ty = r >> 4; }
  else if (bid < 2048) { z = 4;         int r = bid - 1024; tx = r & 63; ty = r >> 6; }
  else                 { z = 5;         int r = bid - 2048; tx = r & 15; ty = r >> 4; }
  const TP a = args.t[z];
  const int t = threadIdx.x;
  const int n0 = tx * 64, k0 = ty * 64;
#pragma unroll
  for (int i = 0; i < 16; i++) {
    int e = i * 256 + t; int r = e >> 6, c = e & 63;
    tile[r][c] = a.s[(size_t)(k0 + r) * a.N + n0 + c];
  }
  __syncthreads();
#pragma unroll
  for (int i = 0; i < 16; i++) {
    int e = i * 256 + t; int r = e >> 6, c = e & 63;
    a.d[(size_t)(n0 + r) * a.K + k0 + c] = (bf16_t)tile[c][r];
  }
}

// ---------------------------------------------------------------------------
// GEMM: C[M][N] = (A[M][K] @ BT[N][K]^T + bias) * scale (+optional relu),
// bf16 in/out, fp32 accum/bias. bias_mode: 0 = bias[col], 1 = bias[row].
// 128x128 tile, BK=32, 16x16x32 MFMA, global_load_lds staging.
// grid (N/128, M/128), block 256 (4 waves, each 64x64).
__global__ __launch_bounds__(256)
void gemm_bt(const bf16_t* __restrict__ A, const bf16_t* __restrict__ BT,
             const float* __restrict__ bias, bf16_t* __restrict__ C,
             int M, int N, int K, int relu, int bias_mode, float scale) {
  __shared__ __align__(16) bf16_t As[128 * 32];
  __shared__ __align__(16) bf16_t Bs[128 * 32];
  const int tid = threadIdx.x;
  const int wave = tid >> 6, lane = tid & 63;
  const int quad = lane >> 4, l15 = lane & 15;
  const long bm = (long)blockIdx.y * 128, bn = (long)blockIdx.x * 128;
  const int wm = (wave >> 1) * 64, wn = (wave & 1) * 64;

  f32x4 acc[4][4];
#pragma unroll
  for (int i = 0; i < 4; i++)
#pragma unroll
    for (int j = 0; j < 4; j++) acc[i][j] = (f32x4){0.f, 0.f, 0.f, 0.f};

  // wave stages rows [wave*32, wave*32+32) of both tiles (2 insts of 16 rows)
  const bf16_t* ag = A + (bm + wave * 32 + (lane >> 2)) * (long)K + (lane & 3) * 8;
  const bf16_t* bg = BT + (bn + wave * 32 + (lane >> 2)) * (long)K + (lane & 3) * 8;
  bf16_t* as_dst = &As[wave * 1024];
  bf16_t* bs_dst = &Bs[wave * 1024];

  for (int k0 = 0; k0 < K; k0 += 32) {
    gload16(ag + k0, as_dst);
    gload16(ag + k0 + (long)16 * K, as_dst + 512);
    gload16(bg + k0, bs_dst);
    gload16(bg + k0 + (long)16 * K, bs_dst + 512);
    __syncthreads();   // drains vmcnt (global_load_lds) + lgkm

    bf16x8 af[4], bf[4];
#pragma unroll
    for (int i = 0; i < 4; i++)
      af[i] = *(const bf16x8*)&As[(wm + i * 16 + l15) * 32 + quad * 8];
#pragma unroll
    for (int i = 0; i < 4; i++)
      bf[i] = *(const bf16x8*)&Bs[(wn + i * 16 + l15) * 32 + quad * 8];
#pragma unroll
    for (int mi = 0; mi < 4; mi++)
#pragma unroll
      for (int ni = 0; ni < 4; ni++)
        acc[mi][ni] = __builtin_amdgcn_mfma_f32_16x16x32_bf16(af[mi], bf[ni], acc[mi][ni], 0, 0, 0);
    __syncthreads();
  }

  // epilogue: C/D layout col=lane&15, row=quad*4+reg (m89-verified)
#pragma unroll
  for (int mi = 0; mi < 4; mi++) {
#pragma unroll
    for (int ni = 0; ni < 4; ni++) {
      const long col = bn + wn + ni * 16 + l15;
      const float bc = bias_mode ? 0.f : bias[col];
#pragma unroll
      for (int r = 0; r < 4; r++) {
        const long row = bm + wm + mi * 16 + quad * 4 + r;
        const float bb = bias_mode ? bias[row] : bc;
        float v = (acc[mi][ni][r] + bb) * scale;
        if (relu) v = v > 0.f ? v : 0.f;
        C[row * N + col] = (bf16_t)v;
      }
    }
  }
}

// ---------------------------------------------------------------------------
// Flash attention, restructured (round 4).
// grid (Lq/128, H, B), block 256 (4 waves). Wave owns 32 queries (2 q-tiles).
// S^T = K.Q^T via mfma(A=K rows, B=Q rows): C-layout col=l15=QUERY -> softmax
// stats are per-lane scalars; only 2 shfl rounds (cross-quad) per tile.
// K and V frags read DIRECT FROM GLOBAL (L2); no tile staging, no barriers in
// the kt loop. P round-trips per-wave-private LDS (union with dead Q stage).
// O accumulated transposed (O^T = V^T.P^T) so alpha/rinv are per-lane.
__global__ __launch_bounds__(256, 4)
void attn(const bf16_t* __restrict__ Q, const bf16_t* __restrict__ Kp,
          const bf16_t* __restrict__ Vt, const float* __restrict__ maskf,
          bf16_t* __restrict__ AO) {
  __shared__ __align__(16) bf16_t QsPs[128 * 64];   // Q stage, then P (union)
  __shared__ float msk[1024];

  const int tid = threadIdx.x;
  const int wave = tid >> 6, lane = tid & 63;
  const int quad = lane >> 4, l15 = lane & 15;
  const int q0 = blockIdx.x * 128;
  const int h = blockIdx.y;
  const int b = blockIdx.z;

  const long base_q = ((long)b * 1024 + q0) * 1024 + h * 64;

  // stage full additive mask for this batch (exp2 domain)
  *(float4*)&msk[tid * 4] = *(const float4*)(maskf + (long)b * 1024 + tid * 4);

  // stage Q tile 128x64, XOR-swizzled 16B blocks by (row&7)
#pragma unroll
  for (int i = 0; i < 4; i++) {
    int e = i * 256 + tid; int r = e >> 3, blk = e & 7;
    const int4 v = *(const int4*)(Q + base_q + (long)r * 1024 + blk * 8);
    *(int4*)&QsPs[r * 64 + ((blk ^ (r & 7)) * 8)] = v;
  }
  __syncthreads();

  // hoist Q B-frags: queries wave*32 + qt*16 + l15
  bf16x8 aq[2][2];
#pragma unroll
  for (int qt = 0; qt < 2; qt++)
#pragma unroll
    for (int ks = 0; ks < 2; ks++) {
      int row = wave * 32 + qt * 16 + l15;
      aq[qt][ks] = *(const bf16x8*)&QsPs[row * 64 + (((ks * 4 + quad) ^ (row & 7)) * 8)];
    }
  __syncthreads();          // Qs dead -> region becomes per-wave P buffers
  bf16_t* Pw = &QsPs[wave * 32 * 64];

  // per-lane global base pointers
  const bf16_t* kb = Kp + ((long)b * 1024 + l15) * 1024 + h * 64 + quad * 8;
  const bf16_t* vb = Vt + ((long)h * 64 + l15) * 8192 + (long)b * 1024 + quad * 8;

  float m_i[2] = {-1e30f, -1e30f}, l_i[2] = {0.f, 0.f};
  f32x4 o[2][4];
#pragma unroll
  for (int qt = 0; qt < 2; qt++)
#pragma unroll
    for (int mt = 0; mt < 4; mt++) o[qt][mt] = (f32x4){0.f, 0.f, 0.f, 0.f};

  for (int kt = 0; kt < 16; kt++) {
    const int k0 = kt * 64;

    // S^T tiles: A = K rows (key = k0+nt*16+l15, d = ks*32+quad*8+j) from L2
    f32x4 sc[4][2];
#pragma unroll
    for (int nt = 0; nt < 4; nt++) {
      sc[nt][0] = (f32x4){0.f, 0.f, 0.f, 0.f};
      sc[nt][1] = (f32x4){0.f, 0.f, 0.f, 0.f};
#pragma unroll
      for (int ks = 0; ks < 2; ks++) {
        const bf16x8 bk = *(const bf16x8*)(kb + (long)(k0 + nt * 16) * 1024 + ks * 32);
#pragma unroll
        for (int qt = 0; qt < 2; qt++)
          sc[nt][qt] = __builtin_amdgcn_mfma_f32_16x16x32_bf16(bk, aq[qt][ks], sc[nt][qt], 0, 0, 0);
      }
    }

    // additive mask per key (key = k0 + nt*16 + quad*4 + r), broadcast reads
    f32x4 mv[4];
#pragma unroll
    for (int nt = 0; nt < 4; nt++)
      mv[nt] = *(const f32x4*)&msk[k0 + nt * 16 + quad * 4];
#pragma unroll
    for (int nt = 0; nt < 4; nt++) {
      sc[nt][0] += mv[nt];
      sc[nt][1] += mv[nt];
    }

    // online softmax per qt: all stats per-lane (query = qt*16 + l15)
#pragma unroll
    for (int qt = 0; qt < 2; qt++) {
      f32x4 m4 = sc[0][qt];
#pragma unroll
      for (int nt = 1; nt < 4; nt++) {
        m4[0] = fmaxf(m4[0], sc[nt][qt][0]); m4[1] = fmaxf(m4[1], sc[nt][qt][1]);
        m4[2] = fmaxf(m4[2], sc[nt][qt][2]); m4[3] = fmaxf(m4[3], sc[nt][qt][3]);
      }
      float mx = fmaxf(fmaxf(m4[0], m4[1]), fmaxf(m4[2], m4[3]));
      mx = fmaxf(mx, __shfl_xor(mx, 16));
      mx = fmaxf(mx, __shfl_xor(mx, 32));
      const float mnew = fmaxf(m_i[qt], mx);
      const float alpha = exp2f(m_i[qt] - mnew);
      m_i[qt] = mnew;
      float ps = 0.f;
#pragma unroll
      for (int nt = 0; nt < 4; nt++)
#pragma unroll
        for (int r = 0; r < 4; r++) {
          float p = exp2f(sc[nt][qt][r] - mnew);
          sc[nt][qt][r] = p;
          ps += p;
        }
      l_i[qt] = l_i[qt] * alpha + ps;   // per-lane partial; cross-quad at end
#pragma unroll
      for (int mt = 0; mt < 4; mt++) o[qt][mt] *= alpha;

      // write P row (query qr), packed 4 keys (quad*4+r) per b64, swizzled
      const int qr = qt * 16 + l15;
#pragma unroll
      for (int nt = 0; nt < 4; nt++) {
        bf16x4 pp;
        pp[0] = (bf16_t)sc[nt][qt][0]; pp[1] = (bf16_t)sc[nt][qt][1];
        pp[2] = (bf16_t)sc[nt][qt][2]; pp[3] = (bf16_t)sc[nt][qt][3];
        const int kblk = nt * 2 + (quad >> 1);
        *(bf16x4*)&Pw[qr * 64 + ((kblk ^ (qr & 7)) * 8) + (quad & 1) * 4] = pp;
      }
    }

    // O^T += V^T . P^T : A = V rows (hd = mt*16+l15) from L2, B = P rows
    bf16x8 bp[2][2];
#pragma unroll
    for (int qt = 0; qt < 2; qt++)
#pragma unroll
      for (int ks = 0; ks < 2; ks++) {
        const int qr = qt * 16 + l15;
        bp[qt][ks] = *(const bf16x8*)&Pw[qr * 64 + (((ks * 4 + quad) ^ (qr & 7)) * 8)];
      }
#pragma unroll
    for (int mt = 0; mt < 4; mt++)
#pragma unroll
      for (int ks = 0; ks < 2; ks++) {
        const bf16x8 av = *(const bf16x8*)(vb + (long)(mt * 16) * 8192 + k0 + ks * 32);
#pragma unroll
        for (int qt = 0; qt < 2; qt++)
          o[qt][mt] = __builtin_amdgcn_mfma_f32_16x16x32_bf16(av, bp[qt][ks], o[qt][mt], 0, 0, 0);
      }
  }

  // epilogue: O^T layout col=query(l15), row=hd(mt*16+quad*4+r)
#pragma unroll
  for (int qt = 0; qt < 2; qt++) {
    float lt = l_i[qt];
    lt += __shfl_xor(lt, 16);
    lt += __shfl_xor(lt, 32);
    const float rinv = 1.0f / lt;
    const long tok = (long)b * 1024 + q0 + wave * 32 + qt * 16 + l15;
#pragma unroll
    for (int mt = 0; mt < 4; mt++) {
      bf16x4 ov;
      ov[0] = (bf16_t)(o[qt][mt][0] * rinv); ov[1] = (bf16_t)(o[qt][mt][1] * rinv);
      ov[2] = (bf16_t)(o[qt][mt][2] * rinv); ov[3] = (bf16_t)(o[qt][mt][3] * rinv);
      *(bf16x4*)&AO[tok * 1024 + h * 64 + mt * 16 + quad * 4] = ov;
    }
  }
}

// ---------------------------------------------------------------------------
// LN1: out_bf16[row] = LN(q_f32[row] + xb_bf16[row]) * g + bt. one block/row.
__global__ __launch_bounds__(256)
void ln_res1(const float* __restrict__ xa, const bf16_t* __restrict__ xb,
             const float* __restrict__ g, const float* __restrict__ bt,
             bf16_t* __restrict__ out) {
  __shared__ float sw[8];
  const int t = threadIdx.x, w = t >> 6;
  const long row = blockIdx.x;
  const float4 a = *(const float4*)(xa + row * 1024 + t * 4);
  const bf16x4 bq = *(const bf16x4*)(xb + row * 1024 + t * 4);
  float v[4] = {a.x + (float)bq[0], a.y + (float)bq[1],
                a.z + (float)bq[2], a.w + (float)bq[3]};
  float s = v[0] + v[1] + v[2] + v[3];
  float s2 = v[0]*v[0] + v[1]*v[1] + v[2]*v[2] + v[3]*v[3];
#pragma unroll
  for (int off = 1; off < 64; off <<= 1) {
    s += __shfl_xor(s, off); s2 += __shfl_xor(s2, off);
  }
  if ((t & 63) == 0) { sw[w] = s; sw[4 + w] = s2; }
  __syncthreads();
  s = sw[0] + sw[1] + sw[2] + sw[3];
  s2 = sw[4] + sw[5] + sw[6] + sw[7];
  const float mean = s * (1.f / 1024.f);
  const float var = s2 * (1.f / 1024.f) - mean * mean;
  const float rstd = rsqrtf(var + 1e-5f);
  bf16x4 o;
#pragma unroll
  for (int i = 0; i < 4; i++) {
    const int c = t * 4 + i;
    o[i] = (bf16_t)((v[i] - mean) * rstd * g[c] + bt[c]);
  }
  *(bf16x4*)(out + row * 1024 + t * 4) = o;
}

// LN2: out_f32[row] = LN(xa_bf16[row] + xb_bf16[row]) * g + bt. one block/row.
__global__ __launch_bounds__(256)
void ln_res2(const bf16_t* __restrict__ xa, const bf16_t* __restrict__ xb,
             const float* __restrict__ g, const float* __restrict__ bt,
             float* __restrict__ out) {
  __shared__ float sw[8];
  const int t = threadIdx.x, w = t >> 6;
  const long row = blockIdx.x;
  const bf16x4 aq = *(const bf16x4*)(xa + row * 1024 + t * 4);
  const bf16x4 bq = *(const bf16x4*)(xb + row * 1024 + t * 4);
  float v[4];
#pragma unroll
  for (int i = 0; i < 4; i++) v[i] = (float)aq[i] + (float)bq[i];
  float s = v[0] + v[1] + v[2] + v[3];
  float s2 = v[0]*v[0] + v[1]*v[1] + v[2]*v[2] + v[3]*v[3];
#pragma unroll
  for (int off = 1; off < 64; off <<= 1) {
    s += __shfl_xor(s, off); s2 += __shfl_xor(s2, off);
  }
  if ((t & 63) == 0) { sw[w] = s; sw[4 + w] = s2; }
  __syncthreads();
  s = sw[0] + sw[1] + sw[2] + sw[3];
  s2 = sw[4] + sw[5] + sw[6] + sw[7];
  const float mean = s * (1.f / 1024.f);
  const float var = s2 * (1.f / 1024.f) - mean * mean;
  const float rstd = rsqrtf(var + 1e-5f);
  float4 o;
  o.x = (v[0] - mean) * rstd * g[t*4+0] + bt[t*4+0];
  o.y = (v[1] - mean) * rstd * g[t*4+1] + bt[t*4+1];
  o.z = (v[2] - mean) * rstd * g[t*4+2] + bt[t*4+2];
  o.w = (v[3] - mean) * rstd * g[t*4+3] + bt[t*4+3];
  *(float4*)(out + row * 1024 + t * 4) = o;
}

// ---------------------------------------------------------------------------
extern "C" void kernel_launch(void* const* d_in, const int* in_sizes, int n_in,
                              void* d_out, int out_size, void* d_ws, size_t ws_size,
                              hipStream_t stream) {
  (void)in_sizes; (void)n_in; (void)out_size; (void)ws_size;
  const float* q   = (const float*)d_in[0];
  const float* kv  = (const float*)d_in[1];
  const unsigned char* mraw = (const unsigned char*)d_in[2];
  const float* Wq = (const float*)d_in[3];
  const float* bq = (const float*)d_in[4];
  const float* Wk = (const float*)d_in[5];
  const float* bk = (const float*)d_in[6];
  const float* Wv = (const float*)d_in[7];
  const float* bv = (const float*)d_in[8];
  const float* Wo = (const float*)d_in[9];
  const float* bo = (const float*)d_in[10];
  const float* g1 = (const float*)d_in[11];
  const float* be1 = (const float*)d_in[12];
  const float* W1 = (const float*)d_in[13];
  const float* b1 = (const float*)d_in[14];
  const float* W2 = (const float*)d_in[15];
  const float* b2 = (const float*)d_in[16];
  const float* g2 = (const float*)d_in[17];
  const float* be2 = (const float*)d_in[18];
  float* out = (float*)d_out;

  char* ws = (char*)d_ws;
  size_t off = 0;
  auto alloc = [&](size_t bytes) -> char* {
    char* p = ws + off; off += (bytes + 255) & ~(size_t)255; return p;
  };
  const size_t MB16 = (size_t)8192 * 1024 * 2;   // one [8192,1024] bf16 buffer
  float*  maskf = (float*)alloc(8192 * 4);
  bf16_t* WqT = (bf16_t*)alloc((size_t)1024 * 1024 * 2);
  bf16_t* WkT = (bf16_t*)alloc((size_t)1024 * 1024 * 2);
  bf16_t* WvT = (bf16_t*)alloc((size_t)1024 * 1024 * 2);
  bf16_t* WoT = (bf16_t*)alloc((size_t)1024 * 1024 * 2);
  bf16_t* W1T = (bf16_t*)alloc((size_t)1024 * 4096 * 2);
  bf16_t* W2T = (bf16_t*)alloc((size_t)4096 * 1024 * 2);
  bf16_t* Qp = (bf16_t*)alloc(MB16);
  bf16_t* Kp = (bf16_t*)alloc(MB16);
  bf16_t* VT = (bf16_t*)alloc(MB16);   // [1024 (h*64+hd)][8192 (b*1024+tok)]
  bf16_t* AO = (bf16_t*)alloc(MB16);
  bf16_t* X1 = (bf16_t*)alloc(MB16);
  bf16_t* TL = (bf16_t*)alloc(MB16);
  // aliases (lifetimes verified):
  bf16_t* qb  = X1;   // bf16 q; dead before ln_res1 writes X1
  bf16_t* kvb = TL;   // bf16 kv; dead after K/V projections
  bf16_t* HF  = Qp;   // [8192,4096] spans Qp..AO; all dead by FFN1
  bf16_t* OP  = Kp;   // o-proj out; Kp dead after attention
  bf16_t* F2  = WqT;  // [8192,1024] spans WqT..W1T (16MB); W2T untouched

  cvt_qkv<<<8192, 256, 0, stream>>>(q, kv, qb, kvb);
  prep_mask<<<8, 256, 0, stream>>>(mraw, maskf);
  TP6 tp = {{ {Wq, WqT, 1024, 1024}, {Wk, WkT, 1024, 1024},
              {Wv, WvT, 1024, 1024}, {Wo, WoT, 1024, 1024},
              {W1, W1T, 1024, 4096}, {W2, W2T, 4096, 1024} }};
  transpose_all<<<3072, 256, 0, stream>>>(tp);

  const dim3 gproj(8, 64);
  // Qp scaled into exp2 score domain
  gemm_bt<<<gproj, 256, 0, stream>>>(qb,  WqT, bq, Qp, 8192, 1024, 1024, 0, 0, QSCALE);
  gemm_bt<<<gproj, 256, 0, stream>>>(kvb, WkT, bk, Kp, 8192, 1024, 1024, 0, 0, 1.f);
  // V projection computed transposed: VT[n][m] = (kv@Wv+bv)^T  (swap operands)
  gemm_bt<<<dim3(64, 8), 256, 0, stream>>>(WvT, kvb, bv, VT, 1024, 8192, 1024, 0, 1, 1.f);

  attn<<<dim3(8, 16, 8), 256, 0, stream>>>(Qp, Kp, VT, maskf, AO);

  gemm_bt<<<gproj, 256, 0, stream>>>(AO, WoT, bo, OP, 8192, 1024, 1024, 0, 0, 1.f);
  ln_res1<<<8192, 256, 0, stream>>>(q, OP, g1, be1, X1);

  gemm_bt<<<dim3(32, 64), 256, 0, stream>>>(X1, W1T, b1, HF, 8192, 4096, 1024, 1, 0, 1.f);
  gemm_bt<<<dim3(8, 64), 256, 0, stream>>>(HF, W2T, b2, F2, 8192, 1024, 4096, 0, 0, 1.f);
  ln_res2<<<8192, 256, 0, stream>>>(X1, F2, g2, be2, out);
}